// Round 14
// baseline (624.951 us; speedup 1.0000x reference)
//
#include <hip/hip_runtime.h>
#include <hip/hip_bf16.h>

#define L_ 2048
#define S_ 2048
#define NB 4
#define E_ 1024
#define H_ 16
#define D_ 64
#define NCH (S_ / 64)

typedef __attribute__((ext_vector_type(8))) short bf16x8;
typedef __attribute__((ext_vector_type(4))) float f32x4;

__device__ __forceinline__ short f2bf(float f) {
  union { float f; unsigned u; } v; v.f = f;
  unsigned r = v.u + 0x7FFFu + ((v.u >> 16) & 1u);
  return (short)(r >> 16);
}
__device__ __forceinline__ float bf2f(short s) {
  union { unsigned u; float f; } v; v.u = ((unsigned)(unsigned short)s) << 16;
  return v.f;
}
// packed f32x2 -> bf16x2 (RNE, same rounding as f2bf)
__device__ __forceinline__ unsigned cvt_pk_bf16(float lo, float hi) {
  unsigned r;
  asm("v_cvt_pk_bf16_f32 %0, %1, %2" : "=v"(r) : "v"(lo), "v"(hi));
  return r;
}
// async global->LDS, 16B per lane; LDS dest must be wave-uniform base (HW adds lane*16)
__device__ __forceinline__ void gld16(const void* g, void* l) {
  __builtin_amdgcn_global_load_lds(
      (const __attribute__((address_space(1))) unsigned*)g,
      (__attribute__((address_space(3))) unsigned*)l, 16, 0, 0);
}

// LDS-visibility-only barrier: does NOT drain vmcnt (global prefetches survive).
#define LGKM_BARRIER() do {                                   \
    asm volatile("s_waitcnt lgkmcnt(0)" ::: "memory");        \
    __builtin_amdgcn_sched_barrier(0);                        \
    __builtin_amdgcn_s_barrier();                             \
    __builtin_amdgcn_sched_barrier(0);                        \
  } while (0)

// ---------------- kernel 1: fp32 -> bf16 (weights AND q/k/v activations) -----
__global__ void k_convert(const float* __restrict__ wi, const float* __restrict__ wo,
                          const float* __restrict__ qin, const float* __restrict__ kin,
                          const float* __restrict__ vin,
                          short* __restrict__ wqkv, short* __restrict__ wout,
                          short* __restrict__ xq, short* __restrict__ xk,
                          short* __restrict__ xv) {
  const int n1 = 3 * E_ * E_ / 4;       // wi float4s
  const int n2 = E_ * E_ / 4;           // wo
  const int n3 = L_ * NB * E_ / 4;      // each activation
  const int total = n1 + n2 + 3 * n3;
  const int stride = gridDim.x * blockDim.x;
  for (int i = blockIdx.x * blockDim.x + threadIdx.x; i < total; i += stride) {
    const float* src; short* dst; int j = i;
    if (j < n1) { src = wi; dst = wqkv; }
    else {
      j -= n1;
      if (j < n2) { src = wo; dst = wout; }
      else {
        j -= n2;
        if (j < n3) { src = qin; dst = xq; }
        else {
          j -= n3;
          if (j < n3) { src = kin; dst = xk; }
          else { j -= n3; src = vin; dst = xv; }
        }
      }
    }
    float4 v = ((const float4*)src)[j];
    uint2 o; o.x = cvt_pk_bf16(v.x, v.y); o.y = cvt_pk_bf16(v.z, v.w);
    *(uint2*)&dst[(size_t)j * 4] = o;
  }
}

// ---------------- kernel 2: fused QKV projection GEMM (all-bf16, gload_lds) --
// q pre-scaled by (1/8)*log2(e) so softmax uses exp2 directly.
// V (mat==2) written directly in blocked-V^T layout [nh][t/32][d][t%32].
__global__ __launch_bounds__(256) void k_qkv(
    const short* __restrict__ xq, const short* __restrict__ xk, const short* __restrict__ xv,
    const short* __restrict__ wbf, const float* __restrict__ bias,
    short* __restrict__ qh, short* __restrict__ kh, short* __restrict__ vt) {
  __shared__ short As[128 * 64];
  __shared__ short Bs[128 * 64];
  const int bm = blockIdx.x;
  const int fbase = blockIdx.y * 128;
  const int mat = fbase >> 10;
  const short* __restrict__ A = (mat == 0) ? xq : (mat == 1) ? xk : xv;
  short* __restrict__ dst = (mat == 0) ? qh : (mat == 1) ? kh : vt;
  const float scale = (mat == 0) ? 0.125f * 1.44269504088896f : 1.0f;
  const int tid = threadIdx.x;
  const int lane = tid & 63, wid = tid >> 6;
  const int wr = wid >> 1, wc = wid & 1;
  const int lr = lane & 15, lk = lane >> 4;
  const int srow = lane >> 3, schk = (lane & 7) * 8;  // staging row/elem within 8-row group
  f32x4 acc[4][4] = {};

  for (int kb = 0; kb < E_; kb += 64) {
    // stage A and B tiles via async global->LDS (16B/lane, 8 rows per instr)
#pragma unroll
    for (int i = 0; i < 4; ++i) {
      const int row0 = wid * 32 + i * 8;
      gld16(&A[(size_t)(bm * 128 + row0 + srow) * E_ + kb + schk], &As[row0 * 64]);
      gld16(&wbf[(size_t)(fbase + row0 + srow) * E_ + kb + schk], &Bs[row0 * 64]);
    }
    __syncthreads();
#pragma unroll
    for (int kk = 0; kk < 2; ++kk) {
      bf16x8 a[4], b[4];
#pragma unroll
      for (int fi = 0; fi < 4; ++fi)
        a[fi] = *(const bf16x8*)&As[(wr * 64 + fi * 16 + lr) * 64 + kk * 32 + lk * 8];
#pragma unroll
      for (int ci = 0; ci < 4; ++ci)
        b[ci] = *(const bf16x8*)&Bs[(wc * 64 + ci * 16 + lr) * 64 + kk * 32 + lk * 8];
#pragma unroll
      for (int fi = 0; fi < 4; ++fi)
#pragma unroll
        for (int ci = 0; ci < 4; ++ci)
          acc[fi][ci] = __builtin_amdgcn_mfma_f32_16x16x32_bf16(a[fi], b[ci], acc[fi][ci], 0, 0, 0);
    }
    __syncthreads();
  }
#pragma unroll
  for (int ci = 0; ci < 4; ++ci) {
    const int fg = fbase + wc * 64 + ci * 16 + lr;
    const float b = bias[fg];
    const int col = fg & 1023;
    const int h = col >> 6, d = col & 63;
#pragma unroll
    for (int fi = 0; fi < 4; ++fi)
#pragma unroll
      for (int j = 0; j < 4; ++j) {
        int m = bm * 128 + wr * 64 + fi * 16 + lk * 4 + j;
        int t = m >> 2, n = m & 3;
        float vv = (acc[fi][ci][j] + b) * scale;
        size_t base = (size_t)(n * H_ + h) * (L_ * D_);
        size_t idx = (mat == 2)
          ? base + (size_t)(t >> 5) * (D_ * 32) + d * 32 + (t & 31)
          : base + ((size_t)t << 6) + d;
        dst[idx] = f2bf(vv);
      }
  }
}

// ---------------- kernel 3: softmax denominators (reciprocal) ----------------
__global__ __launch_bounds__(256) void k_stats(
    const short* __restrict__ qh, const short* __restrict__ kh, float* __restrict__ rl) {
  const int nh = blockIdx.y;
  const int qt = blockIdx.x;
  const short* __restrict__ Q = qh + (size_t)nh * L_ * D_;
  const short* __restrict__ K = kh + (size_t)nh * S_ * D_;
  const int tid = threadIdx.x;
  const int lane = tid & 63, wid = tid >> 6;
  const int lr = lane & 15, lk = lane >> 4;
  const int rbase = qt * 128 + wid * 32;
  bf16x8 a[2][2];
#pragma unroll
  for (int ri = 0; ri < 2; ++ri)
#pragma unroll
    for (int kk = 0; kk < 2; ++kk)
      a[ri][kk] = *(const bf16x8*)&Q[(size_t)(rbase + ri * 16 + lr) * D_ + kk * 32 + lk * 8];
  bf16x8 kst[4][2];
#pragma unroll
  for (int ci = 0; ci < 4; ++ci) {
    kst[ci][0] = *(const bf16x8*)&K[(size_t)(ci * 16 + lr) * D_ + lk * 8];
    kst[ci][1] = *(const bf16x8*)&K[(size_t)(ci * 16 + lr) * D_ + 32 + lk * 8];
  }
  float ssum[2][4] = {};
  for (int st = 0; st < S_; st += 64) {
    const int stn = (st + 64 < S_) ? st + 64 : st;
    f32x4 acc[2][4] = {};
#pragma unroll
    for (int ci = 0; ci < 4; ++ci) {
#pragma unroll
      for (int ri = 0; ri < 2; ++ri) {
        acc[ri][ci] = __builtin_amdgcn_mfma_f32_16x16x32_bf16(a[ri][0], kst[ci][0], acc[ri][ci], 0, 0, 0);
        acc[ri][ci] = __builtin_amdgcn_mfma_f32_16x16x32_bf16(a[ri][1], kst[ci][1], acc[ri][ci], 0, 0, 0);
      }
      kst[ci][0] = *(const bf16x8*)&K[(size_t)(stn + ci * 16 + lr) * D_ + lk * 8];
      kst[ci][1] = *(const bf16x8*)&K[(size_t)(stn + ci * 16 + lr) * D_ + 32 + lk * 8];
    }
#pragma unroll
    for (int ri = 0; ri < 2; ++ri)
#pragma unroll
      for (int j = 0; j < 4; ++j) {
        float s = __builtin_amdgcn_exp2f(acc[ri][0][j]) + __builtin_amdgcn_exp2f(acc[ri][1][j]) +
                  __builtin_amdgcn_exp2f(acc[ri][2][j]) + __builtin_amdgcn_exp2f(acc[ri][3][j]);
        s += __shfl_xor(s, 1);
        s += __shfl_xor(s, 2);
        s += __shfl_xor(s, 4);
        s += __shfl_xor(s, 8);
        ssum[ri][j] += s;
      }
  }
  if (lr == 0) {
#pragma unroll
    for (int ri = 0; ri < 2; ++ri)
#pragma unroll
      for (int j = 0; j < 4; ++j)
        rl[(size_t)nh * L_ + rbase + ri * 16 + lk * 4 + j] = 1.0f / ssum[ri][j];
  }
}

// ---------------- kernel 4: attention (R8 + register-dbuf prefetch) ---------
// 1D grid 256, XCD decode: n=(bid&7)>>1, qt=(bid>>3)|((bid&1)<<5).
// 1024 threads = 16 waves (1 head each); 64-S chunks; psl dbuf 2x64KB;
// one lgkm-only barrier per chunk. K/V register fragments double-buffered
// with STATIC parity (2-chunk unrolled body): chunk t+1's 24 loads issue at
// the top of chunk t's compute and stay in flight across the lgkm-only
// barrier; their waitcnt lands at first use a full phase later.
#define LOAD_CHUNK(KF, VB, ST) do {                                            \
    _Pragma("unroll") for (int u = 0; u < 4; ++u) {                            \
      KF[u][0] = *(const bf16x8*)&K[(size_t)((ST) + u * 16 + lr) * D_ + lk * 8];       \
      KF[u][1] = *(const bf16x8*)&K[(size_t)((ST) + u * 16 + lr) * D_ + 32 + lk * 8];  \
    }                                                                          \
    _Pragma("unroll") for (int b = 0; b < 2; ++b) {                            \
      const size_t sb_ = (size_t)(((ST) >> 5) + b) * (D_ * 32);                \
      _Pragma("unroll") for (int ci = 0; ci < 4; ++ci)                         \
        VB[ci][b] = *(const bf16x8*)&VT[sb_ + (ci * 16 + lr) * 32 + lk * 8];   \
    }                                                                          \
  } while (0)

#define COMPUTE_CHUNK(KF, VB, SL) do {                                         \
    _Pragma("unroll") for (int u = 0; u < 4; ++u) {                            \
      _Pragma("unroll") for (int li = 0; li < 2; ++li) {                       \
        f32x4 sc = {};                                                         \
        sc = __builtin_amdgcn_mfma_f32_16x16x32_bf16(KF[u][0], qf[li][0], sc, 0, 0, 0); \
        sc = __builtin_amdgcn_mfma_f32_16x16x32_bf16(KF[u][1], qf[li][1], sc, 0, 0, 0); \
        uint2 pk;                                                              \
        pk.x = cvt_pk_bf16(__builtin_amdgcn_exp2f(sc[0]) * rls[li],            \
                           __builtin_amdgcn_exp2f(sc[1]) * rls[li]);           \
        pk.y = cvt_pk_bf16(__builtin_amdgcn_exp2f(sc[2]) * rls[li],            \
                           __builtin_amdgcn_exp2f(sc[3]) * rls[li]);           \
        const int row = li * 16 + lr;                                          \
        *(uint2*)((SL) + row * 128 + ((u * 32 + lk * 8) ^ ((row & 7) << 4))) = pk; \
      }                                                                        \
    }                                                                          \
    _Pragma("unroll") for (int b = 0; b < 2; ++b)                              \
      _Pragma("unroll") for (int li = 0; li < 2; ++li) {                       \
        const int row = li * 16 + lr;                                          \
        bf16x8 pa = *(const bf16x8*)((SL) + row * 128 + ((b * 64 + lk * 16) ^ ((row & 7) << 4))); \
        _Pragma("unroll") for (int ci = 0; ci < 4; ++ci)                       \
          cacc[li][ci] = __builtin_amdgcn_mfma_f32_16x16x32_bf16(pa, VB[ci][b], cacc[li][ci], 0, 0, 0); \
      }                                                                        \
  } while (0)

#define MEAN_CHUNK(MSBUF, STW) do {                                            \
    float s0 = 0.f, s1 = 0.f;                                                  \
    _Pragma("unroll") for (int hh = 0; hh < 16; ++hh) {                        \
      short2 m = *(const short2*)((MSBUF) + hh * 4096 + moff);                 \
      s0 += bf2f(m.x); s1 += bf2f(m.y);                                        \
    }                                                                          \
    *(float2*)&awp[(STW)] = make_float2(s0 * 0.0625f, s1 * 0.0625f);           \
  } while (0)

__global__ __launch_bounds__(1024) void k_attn(
    const short* __restrict__ qh, const short* __restrict__ kh, const short* __restrict__ vt,
    const float* __restrict__ rl, float* __restrict__ attnw, short* __restrict__ ctx) {
  extern __shared__ char psl[];  // [2][16 heads][32 rows][128B], byte ^= (row&7)<<4
  const int bid = blockIdx.x;
  const int xcd = bid & 7;
  const int n = xcd >> 1;
  const int qt = (bid >> 3) | ((xcd & 1) << 5);
  const int tid = threadIdx.x;
  const int h = tid >> 6, lane = tid & 63;
  const int lr = lane & 15, lk = lane >> 4;
  const int rbase = qt * 32;
  const size_t nh = (size_t)(n * H_ + h);
  const short* __restrict__ K = kh + nh * S_ * D_;
  const short* __restrict__ VT = vt + nh * S_ * D_;
  char* const slab0 = psl + h * 4096;           // buffer0 slab
  char* const slab1 = psl + 65536 + h * 4096;   // buffer1 slab

  bf16x8 qf[2][2];
  float rls[2];
  {
    const short* Q = qh + nh * L_ * D_;
#pragma unroll
    for (int li = 0; li < 2; ++li) {
#pragma unroll
      for (int kk = 0; kk < 2; ++kk)
        qf[li][kk] = *(const bf16x8*)&Q[(size_t)(rbase + li * 16 + lr) * D_ + kk * 32 + lk * 8];
      rls[li] = rl[nh * L_ + rbase + li * 16 + lr];
    }
  }
  f32x4 cacc[2][4] = {};
  // mean-phase geometry: 1024 threads cover 32 rows x 64 cols (2 cols each)
  const int mrow = tid >> 5, mc2 = (tid & 31) * 2;
  float* awp = attnw + ((size_t)n * L_ + rbase + mrow) * S_ + mc2;
  const int moff = mrow * 128 + ((mc2 * 2) ^ ((mrow & 7) << 4));  // byte offset

  bf16x8 kfA[4][2], vbA[4][2], kfB[4][2], vbB[4][2];
  LOAD_CHUNK(kfA, vbA, 0);  // preload chunk 0

  for (int chp = 0; chp < NCH; chp += 2) {
    const int stA = chp * 64;
    const int stB = stA + 64;
    const int stC = (chp + 2 < NCH) ? stA + 128 : stA + 64;  // clamped prefetch
    // ---- sub A: chunk chp (even) -> psl buffer 0
    LOAD_CHUNK(kfB, vbB, stB);           // prefetch chunk chp+1 (in flight across barrier)
    COMPUTE_CHUNK(kfA, vbA, slab0);
    if (chp > 0) MEAN_CHUNK(psl + 65536, stA - 64);  // chunk chp-1 (odd) from buffer 1
    LGKM_BARRIER();
    // ---- sub B: chunk chp+1 (odd) -> psl buffer 1
    LOAD_CHUNK(kfA, vbA, stC);           // prefetch chunk chp+2
    COMPUTE_CHUNK(kfB, vbB, slab1);
    MEAN_CHUNK(psl, stA);                // chunk chp (even) from buffer 0
    LGKM_BARRIER();
  }
  // ---- final chunk's mean (chunk NCH-1 odd -> buffer 1)
  MEAN_CHUNK(psl + 65536, S_ - 64);
  // ---- ctx write: [l][n][h*64+d] bf16
#pragma unroll
  for (int li = 0; li < 2; ++li)
#pragma unroll
    for (int ci = 0; ci < 4; ++ci)
#pragma unroll
      for (int j = 0; j < 4; ++j) {
        int row = rbase + li * 16 + lk * 4 + j;
        int d = ci * 16 + lr;
        ctx[((size_t)row * NB + n) * E_ + h * 64 + d] = f2bf(cacc[li][ci][j]);
      }
}

// ---------------- kernel 5: output projection (all-bf16, gload_lds) ---------
__global__ __launch_bounds__(256) void k_out(
    const short* __restrict__ ctxb, const short* __restrict__ wbf,
    const float* __restrict__ bias, float* __restrict__ out) {
  __shared__ short As[128 * 64];
  __shared__ short Bs[128 * 64];
  const int bm = blockIdx.x, bn = blockIdx.y;
  const int tid = threadIdx.x;
  const int lane = tid & 63, wid = tid >> 6;
  const int wr = wid >> 1, wc = wid & 1;
  const int lr = lane & 15, lk = lane >> 4;
  const int srow = lane >> 3, schk = (lane & 7) * 8;
  f32x4 acc[4][4] = {};
  for (int kb = 0; kb < E_; kb += 64) {
#pragma unroll
    for (int i = 0; i < 4; ++i) {
      const int row0 = wid * 32 + i * 8;
      gld16(&ctxb[(size_t)(bm * 128 + row0 + srow) * E_ + kb + schk], &As[row0 * 64]);
      gld16(&wbf[(size_t)(bn * 128 + row0 + srow) * E_ + kb + schk], &Bs[row0 * 64]);
    }
    __syncthreads();
#pragma unroll
    for (int kk = 0; kk < 2; ++kk) {
      bf16x8 a[4], b[4];
#pragma unroll
      for (int fi = 0; fi < 4; ++fi)
        a[fi] = *(const bf16x8*)&As[(wr * 64 + fi * 16 + lr) * 64 + kk * 32 + lk * 8];
#pragma unroll
      for (int ci = 0; ci < 4; ++ci)
        b[ci] = *(const bf16x8*)&Bs[(wc * 64 + ci * 16 + lr) * 64 + kk * 32 + lk * 8];
#pragma unroll
      for (int fi = 0; fi < 4; ++fi)
#pragma unroll
        for (int ci = 0; ci < 4; ++ci)
          acc[fi][ci] = __builtin_amdgcn_mfma_f32_16x16x32_bf16(a[fi], b[ci], acc[fi][ci], 0, 0, 0);
    }
    __syncthreads();
  }
#pragma unroll
  for (int ci = 0; ci < 4; ++ci) {
    int col = bn * 128 + wc * 64 + ci * 16 + lr;
    float b = bias[col];
#pragma unroll
    for (int fi = 0; fi < 4; ++fi)
#pragma unroll
      for (int j = 0; j < 4; ++j) {
        int m = bm * 128 + wr * 64 + fi * 16 + lk * 4 + j;
        out[(size_t)m * E_ + col] = acc[fi][ci][j] + b;
      }
  }
}

extern "C" void kernel_launch(void* const* d_in, const int* in_sizes, int n_in,
                              void* d_out, int out_size, void* d_ws, size_t ws_size,
                              hipStream_t stream) {
  const float* qin = (const float*)d_in[0];
  const float* kin = (const float*)d_in[1];
  const float* vin = (const float*)d_in[2];
  const float* wi  = (const float*)d_in[3];
  const float* bi  = (const float*)d_in[4];
  const float* wo  = (const float*)d_in[5];
  const float* bo  = (const float*)d_in[6];
  float* out = (float*)d_out;                       // (L,NB,E) fp32
  float* attnw = out + (size_t)L_ * NB * E_;        // (NB,L,S) fp32

  short* wqkv = (short*)d_ws;                       // 3E*E bf16
  short* wout = wqkv + (size_t)3 * E_ * E_;         // E*E bf16
  short* qh = wout + (size_t)E_ * E_;               // NB*H*L*D bf16
  short* kh = qh + (size_t)NB * L_ * E_;
  short* vt = kh + (size_t)NB * L_ * E_;            // NB*H*(S/32)*D*32 bf16 (blocked V^T)
  float* rl = (float*)(vt + (size_t)NB * L_ * E_);  // NB*H*L fp32
  short* xq = (short*)(rl + (size_t)NB * H_ * L_);  // L*NB*E bf16 activations
  short* xk = xq + (size_t)L_ * NB * E_;
  short* xv = xk + (size_t)L_ * NB * E_;
  short* ctx = xq;  // alias: xq dead after k_qkv, ctx written by k_attn

  k_convert<<<2048, 256, 0, stream>>>(wi, wo, qin, kin, vin, wqkv, wout, xq, xk, xv);
  k_qkv<<<dim3(64, 24), 256, 0, stream>>>(xq, xk, xv, wqkv, bi, qh, kh, vt);
  k_stats<<<dim3(16, 64), 256, 0, stream>>>(qh, kh, rl);
  k_attn<<<256, 1024, 131072, stream>>>(qh, kh, vt, rl, attnw, ctx);
  k_out<<<dim3(64, 8), 256, 0, stream>>>(ctx, wout, bo, out);
}

// Round 15
// 464.138 us; speedup vs baseline: 1.3465x; 1.3465x over previous
//
#include <hip/hip_runtime.h>
#include <hip/hip_bf16.h>

#define L_ 2048
#define S_ 2048
#define NB 4
#define E_ 1024
#define H_ 16
#define D_ 64
#define NCH (S_ / 64)

typedef __attribute__((ext_vector_type(8))) short bf16x8;
typedef __attribute__((ext_vector_type(4))) float f32x4;

__device__ __forceinline__ short f2bf(float f) {
  union { float f; unsigned u; } v; v.f = f;
  unsigned r = v.u + 0x7FFFu + ((v.u >> 16) & 1u);
  return (short)(r >> 16);
}
__device__ __forceinline__ float bf2f(short s) {
  union { unsigned u; float f; } v; v.u = ((unsigned)(unsigned short)s) << 16;
  return v.f;
}
// packed f32x2 -> bf16x2 (RNE, same rounding as f2bf)
__device__ __forceinline__ unsigned cvt_pk_bf16(float lo, float hi) {
  unsigned r;
  asm("v_cvt_pk_bf16_f32 %0, %1, %2" : "=v"(r) : "v"(lo), "v"(hi));
  return r;
}
// async global->LDS, 16B per lane; LDS dest must be wave-uniform base (HW adds lane*16)
__device__ __forceinline__ void gld16(const void* g, void* l) {
  __builtin_amdgcn_global_load_lds(
      (const __attribute__((address_space(1))) unsigned*)g,
      (__attribute__((address_space(3))) unsigned*)l, 16, 0, 0);
}

// LDS-visibility-only barrier: does NOT drain vmcnt (global prefetches survive).
#define LGKM_BARRIER() do {                                   \
    asm volatile("s_waitcnt lgkmcnt(0)" ::: "memory");        \
    __builtin_amdgcn_sched_barrier(0);                        \
    __builtin_amdgcn_s_barrier();                             \
    __builtin_amdgcn_sched_barrier(0);                        \
  } while (0)

// ---------------- kernel 1: fp32 -> bf16 (weights AND q/k/v activations) -----
__global__ void k_convert(const float* __restrict__ wi, const float* __restrict__ wo,
                          const float* __restrict__ qin, const float* __restrict__ kin,
                          const float* __restrict__ vin,
                          short* __restrict__ wqkv, short* __restrict__ wout,
                          short* __restrict__ xq, short* __restrict__ xk,
                          short* __restrict__ xv) {
  const int n1 = 3 * E_ * E_ / 4;       // wi float4s
  const int n2 = E_ * E_ / 4;           // wo
  const int n3 = L_ * NB * E_ / 4;      // each activation
  const int total = n1 + n2 + 3 * n3;
  const int stride = gridDim.x * blockDim.x;
  for (int i = blockIdx.x * blockDim.x + threadIdx.x; i < total; i += stride) {
    const float* src; short* dst; int j = i;
    if (j < n1) { src = wi; dst = wqkv; }
    else {
      j -= n1;
      if (j < n2) { src = wo; dst = wout; }
      else {
        j -= n2;
        if (j < n3) { src = qin; dst = xq; }
        else {
          j -= n3;
          if (j < n3) { src = kin; dst = xk; }
          else { j -= n3; src = vin; dst = xv; }
        }
      }
    }
    float4 v = ((const float4*)src)[j];
    uint2 o; o.x = cvt_pk_bf16(v.x, v.y); o.y = cvt_pk_bf16(v.z, v.w);
    *(uint2*)&dst[(size_t)j * 4] = o;
  }
}

// ---------------- kernel 2: fused QKV projection GEMM (bf16, gload_lds) ------
// XCD-affinity decode: bm pinned to one XCD so its A tile (256KB bf16) stays
// L2-resident across all 24 fbase re-uses; mat-major so per-XCD A set = 2MB.
// q pre-scaled by (1/8)*log2(e); V (mat==2) written in blocked-V^T layout.
__global__ __launch_bounds__(256) void k_qkv(
    const short* __restrict__ xq, const short* __restrict__ xk, const short* __restrict__ xv,
    const short* __restrict__ wbf, const float* __restrict__ bias,
    short* __restrict__ qh, short* __restrict__ kh, short* __restrict__ vt) {
  __shared__ short As[128 * 64];
  __shared__ short Bs[128 * 64];
  const int bid = blockIdx.x;
  const int xcd = bid & 7;
  const int r = bid >> 3;           // 0..191
  const int mat = r >> 6;           // 0..2
  const int rr = r & 63;
  const int fb = rr >> 3;           // 0..7
  const int bm = xcd * 8 + (rr & 7);
  const int fbase = mat * 1024 + fb * 128;
  const short* __restrict__ A = (mat == 0) ? xq : (mat == 1) ? xk : xv;
  short* __restrict__ dst = (mat == 0) ? qh : (mat == 1) ? kh : vt;
  const float scale = (mat == 0) ? 0.125f * 1.44269504088896f : 1.0f;
  const int tid = threadIdx.x;
  const int lane = tid & 63, wid = tid >> 6;
  const int wr = wid >> 1, wc = wid & 1;
  const int lr = lane & 15, lk = lane >> 4;
  const int srow = lane >> 3, schk = (lane & 7) * 8;  // staging row/elem within 8-row group
  f32x4 acc[4][4] = {};

  for (int kb = 0; kb < E_; kb += 64) {
    // stage A and B tiles via async global->LDS (16B/lane, 8 rows per instr)
#pragma unroll
    for (int i = 0; i < 4; ++i) {
      const int row0 = wid * 32 + i * 8;
      gld16(&A[(size_t)(bm * 128 + row0 + srow) * E_ + kb + schk], &As[row0 * 64]);
      gld16(&wbf[(size_t)(fbase + row0 + srow) * E_ + kb + schk], &Bs[row0 * 64]);
    }
    __syncthreads();
#pragma unroll
    for (int kk = 0; kk < 2; ++kk) {
      bf16x8 a[4], b[4];
#pragma unroll
      for (int fi = 0; fi < 4; ++fi)
        a[fi] = *(const bf16x8*)&As[(wr * 64 + fi * 16 + lr) * 64 + kk * 32 + lk * 8];
#pragma unroll
      for (int ci = 0; ci < 4; ++ci)
        b[ci] = *(const bf16x8*)&Bs[(wc * 64 + ci * 16 + lr) * 64 + kk * 32 + lk * 8];
#pragma unroll
      for (int fi = 0; fi < 4; ++fi)
#pragma unroll
        for (int ci = 0; ci < 4; ++ci)
          acc[fi][ci] = __builtin_amdgcn_mfma_f32_16x16x32_bf16(a[fi], b[ci], acc[fi][ci], 0, 0, 0);
    }
    __syncthreads();
  }
#pragma unroll
  for (int ci = 0; ci < 4; ++ci) {
    const int fg = fbase + wc * 64 + ci * 16 + lr;
    const float b = bias[fg];
    const int col = fg & 1023;
    const int h = col >> 6, d = col & 63;
#pragma unroll
    for (int fi = 0; fi < 4; ++fi)
#pragma unroll
      for (int j = 0; j < 4; ++j) {
        int m = bm * 128 + wr * 64 + fi * 16 + lk * 4 + j;
        int t = m >> 2, n = m & 3;
        float vv = (acc[fi][ci][j] + b) * scale;
        size_t base = (size_t)(n * H_ + h) * (L_ * D_);
        size_t idx = (mat == 2)
          ? base + (size_t)(t >> 5) * (D_ * 32) + d * 32 + (t & 31)
          : base + ((size_t)t << 6) + d;
        dst[idx] = f2bf(vv);
      }
  }
}

// ---------------- kernel 3: softmax denominators (reciprocal) ----------------
// XCD-affinity: nh pinned to one XCD -> its K (256KB) L2-resident over 16 qt.
__global__ __launch_bounds__(256) void k_stats(
    const short* __restrict__ qh, const short* __restrict__ kh, float* __restrict__ rl) {
  const int bid = blockIdx.x;
  const int xcd = bid & 7;
  const int r = bid >> 3;           // 0..127
  const int nh = xcd * 8 + (r & 7);
  const int qt = r >> 3;            // 0..15
  const short* __restrict__ Q = qh + (size_t)nh * L_ * D_;
  const short* __restrict__ K = kh + (size_t)nh * S_ * D_;
  const int tid = threadIdx.x;
  const int lane = tid & 63, wid = tid >> 6;
  const int lr = lane & 15, lk = lane >> 4;
  const int rbase = qt * 128 + wid * 32;
  bf16x8 a[2][2];
#pragma unroll
  for (int ri = 0; ri < 2; ++ri)
#pragma unroll
    for (int kk = 0; kk < 2; ++kk)
      a[ri][kk] = *(const bf16x8*)&Q[(size_t)(rbase + ri * 16 + lr) * D_ + kk * 32 + lk * 8];
  bf16x8 kst[4][2];
#pragma unroll
  for (int ci = 0; ci < 4; ++ci) {
    kst[ci][0] = *(const bf16x8*)&K[(size_t)(ci * 16 + lr) * D_ + lk * 8];
    kst[ci][1] = *(const bf16x8*)&K[(size_t)(ci * 16 + lr) * D_ + 32 + lk * 8];
  }
  float ssum[2][4] = {};
  for (int st = 0; st < S_; st += 64) {
    const int stn = (st + 64 < S_) ? st + 64 : st;
    f32x4 acc[2][4] = {};
#pragma unroll
    for (int ci = 0; ci < 4; ++ci) {
#pragma unroll
      for (int ri = 0; ri < 2; ++ri) {
        acc[ri][ci] = __builtin_amdgcn_mfma_f32_16x16x32_bf16(a[ri][0], kst[ci][0], acc[ri][ci], 0, 0, 0);
        acc[ri][ci] = __builtin_amdgcn_mfma_f32_16x16x32_bf16(a[ri][1], kst[ci][1], acc[ri][ci], 0, 0, 0);
      }
      kst[ci][0] = *(const bf16x8*)&K[(size_t)(stn + ci * 16 + lr) * D_ + lk * 8];
      kst[ci][1] = *(const bf16x8*)&K[(size_t)(stn + ci * 16 + lr) * D_ + 32 + lk * 8];
    }
#pragma unroll
    for (int ri = 0; ri < 2; ++ri)
#pragma unroll
      for (int j = 0; j < 4; ++j) {
        float s = __builtin_amdgcn_exp2f(acc[ri][0][j]) + __builtin_amdgcn_exp2f(acc[ri][1][j]) +
                  __builtin_amdgcn_exp2f(acc[ri][2][j]) + __builtin_amdgcn_exp2f(acc[ri][3][j]);
        s += __shfl_xor(s, 1);
        s += __shfl_xor(s, 2);
        s += __shfl_xor(s, 4);
        s += __shfl_xor(s, 8);
        ssum[ri][j] += s;
      }
  }
  if (lr == 0) {
#pragma unroll
    for (int ri = 0; ri < 2; ++ri)
#pragma unroll
      for (int j = 0; j < 4; ++j)
        rl[(size_t)nh * L_ + rbase + ri * 16 + lk * 4 + j] = 1.0f / ssum[ri][j];
  }
}

// ---------------- kernel 4: attention (R8/R13 config — frozen) ----------------
// 1D grid 256, XCD decode: n=(bid&7)>>1, qt=(bid>>3)|((bid&1)<<5).
// 1024 threads = 16 waves (1 head each); 64-S chunks; psl dbuf 2x64KB;
// one lgkm-only barrier per chunk (mean of chunk t-1 overlaps compute of t).
__global__ __launch_bounds__(1024) void k_attn(
    const short* __restrict__ qh, const short* __restrict__ kh, const short* __restrict__ vt,
    const float* __restrict__ rl, float* __restrict__ attnw, short* __restrict__ ctx) {
  extern __shared__ char psl[];  // [2][16 heads][32 rows][128B], byte ^= (row&7)<<4
  const int bid = blockIdx.x;
  const int xcd = bid & 7;
  const int n = xcd >> 1;
  const int qt = (bid >> 3) | ((xcd & 1) << 5);
  const int tid = threadIdx.x;
  const int h = tid >> 6, lane = tid & 63;
  const int lr = lane & 15, lk = lane >> 4;
  const int rbase = qt * 32;
  const size_t nh = (size_t)(n * H_ + h);
  const short* __restrict__ K = kh + nh * S_ * D_;
  const short* __restrict__ VT = vt + nh * S_ * D_;
  char* const slab0 = psl + h * 4096;

  bf16x8 qf[2][2];
  float rls[2];
  {
    const short* Q = qh + nh * L_ * D_;
#pragma unroll
    for (int li = 0; li < 2; ++li) {
#pragma unroll
      for (int kk = 0; kk < 2; ++kk)
        qf[li][kk] = *(const bf16x8*)&Q[(size_t)(rbase + li * 16 + lr) * D_ + kk * 32 + lk * 8];
      rls[li] = rl[nh * L_ + rbase + li * 16 + lr];
    }
  }
  f32x4 cacc[2][4] = {};
  // mean-phase geometry: 1024 threads cover 32 rows x 64 cols (2 cols each)
  const int mrow = tid >> 5, mc2 = (tid & 31) * 2;
  float* awp = attnw + ((size_t)n * L_ + rbase + mrow) * S_ + mc2;
  const int moff = mrow * 128 + ((mc2 * 2) ^ ((mrow & 7) << 4));  // byte offset

  for (int ch = 0; ch < NCH; ++ch) {
    const int st = ch * 64;
    char* const sl = slab0 + (ch & 1) * 65536;
    // ---- loads for this chunk: K first (used first), then V
    bf16x8 kf[4][2];
#pragma unroll
    for (int u = 0; u < 4; ++u) {
      kf[u][0] = *(const bf16x8*)&K[(size_t)(st + u * 16 + lr) * D_ + lk * 8];
      kf[u][1] = *(const bf16x8*)&K[(size_t)(st + u * 16 + lr) * D_ + 32 + lk * 8];
    }
    bf16x8 vb[4][2];
#pragma unroll
    for (int b = 0; b < 2; ++b) {
      const size_t sb = (size_t)((st >> 5) + b) * (D_ * 32);
#pragma unroll
      for (int ci = 0; ci < 4; ++ci)
        vb[ci][b] = *(const bf16x8*)&VT[sb + (ci * 16 + lr) * 32 + lk * 8];
    }
    // ---- QK^T (swapped: rows=s, cols=l) per 16-s subtile; p -> swizzled LDS
#pragma unroll
    for (int u = 0; u < 4; ++u) {
#pragma unroll
      for (int li = 0; li < 2; ++li) {
        f32x4 sc = {};
        sc = __builtin_amdgcn_mfma_f32_16x16x32_bf16(kf[u][0], qf[li][0], sc, 0, 0, 0);
        sc = __builtin_amdgcn_mfma_f32_16x16x32_bf16(kf[u][1], qf[li][1], sc, 0, 0, 0);
        uint2 pk;
        pk.x = cvt_pk_bf16(__builtin_amdgcn_exp2f(sc[0]) * rls[li],
                           __builtin_amdgcn_exp2f(sc[1]) * rls[li]);
        pk.y = cvt_pk_bf16(__builtin_amdgcn_exp2f(sc[2]) * rls[li],
                           __builtin_amdgcn_exp2f(sc[3]) * rls[li]);
        const int row = li * 16 + lr;
        *(uint2*)(sl + row * 128 + ((u * 32 + lk * 8) ^ ((row & 7) << 4))) = pk;
      }
    }
    // ---- PV from own slab (wave-local RAW)
#pragma unroll
    for (int b = 0; b < 2; ++b)
#pragma unroll
      for (int li = 0; li < 2; ++li) {
        const int row = li * 16 + lr;
        bf16x8 pa = *(const bf16x8*)(sl + row * 128 + ((b * 64 + lk * 16) ^ ((row & 7) << 4)));
#pragma unroll
        for (int ci = 0; ci < 4; ++ci)
          cacc[li][ci] = __builtin_amdgcn_mfma_f32_16x16x32_bf16(pa, vb[ci][b], cacc[li][ci], 0, 0, 0);
      }
    // ---- head-mean of PREVIOUS chunk (other buffer; overlaps this chunk)
    if (ch > 0) {
      char* const ms = psl + (((ch & 1) ^ 1)) * 65536;
      float s0 = 0.f, s1 = 0.f;
#pragma unroll
      for (int hh = 0; hh < 16; ++hh) {
        short2 m = *(const short2*)(ms + hh * 4096 + moff);
        s0 += bf2f(m.x); s1 += bf2f(m.y);
      }
      *(float2*)&awp[st - 64] = make_float2(s0 * 0.0625f, s1 * 0.0625f);
    }
    LGKM_BARRIER();  // publish chunk ch; mean reads of ch-1 complete
  }
  // ---- final chunk's mean (chunk NCH-1 lives in buffer 1)
  {
    char* const ms = psl + 65536;
    float s0 = 0.f, s1 = 0.f;
#pragma unroll
    for (int hh = 0; hh < 16; ++hh) {
      short2 m = *(const short2*)(ms + hh * 4096 + moff);
      s0 += bf2f(m.x); s1 += bf2f(m.y);
    }
    *(float2*)&awp[S_ - 64] = make_float2(s0 * 0.0625f, s1 * 0.0625f);
  }
  // ---- ctx write: [l][n][h*64+d] bf16
#pragma unroll
  for (int li = 0; li < 2; ++li)
#pragma unroll
    for (int ci = 0; ci < 4; ++ci)
#pragma unroll
      for (int j = 0; j < 4; ++j) {
        int row = rbase + li * 16 + lk * 4 + j;
        int d = ci * 16 + lr;
        ctx[((size_t)row * NB + n) * E_ + h * 64 + d] = f2bf(cacc[li][ci][j]);
      }
}

// ---------------- kernel 5: output projection (bf16, gload_lds, XCD-affinity)
__global__ __launch_bounds__(256) void k_out(
    const short* __restrict__ ctxb, const short* __restrict__ wbf,
    const float* __restrict__ bias, float* __restrict__ out) {
  __shared__ short As[128 * 64];
  __shared__ short Bs[128 * 64];
  const int bid = blockIdx.x;
  const int xcd = bid & 7;
  const int r = bid >> 3;           // 0..63
  const int bm = xcd * 8 + (r & 7);
  const int bn = r >> 3;            // 0..7
  const int tid = threadIdx.x;
  const int lane = tid & 63, wid = tid >> 6;
  const int wr = wid >> 1, wc = wid & 1;
  const int lr = lane & 15, lk = lane >> 4;
  const int srow = lane >> 3, schk = (lane & 7) * 8;
  f32x4 acc[4][4] = {};
  for (int kb = 0; kb < E_; kb += 64) {
#pragma unroll
    for (int i = 0; i < 4; ++i) {
      const int row0 = wid * 32 + i * 8;
      gld16(&ctxb[(size_t)(bm * 128 + row0 + srow) * E_ + kb + schk], &As[row0 * 64]);
      gld16(&wbf[(size_t)(bn * 128 + row0 + srow) * E_ + kb + schk], &Bs[row0 * 64]);
    }
    __syncthreads();
#pragma unroll
    for (int kk = 0; kk < 2; ++kk) {
      bf16x8 a[4], b[4];
#pragma unroll
      for (int fi = 0; fi < 4; ++fi)
        a[fi] = *(const bf16x8*)&As[(wr * 64 + fi * 16 + lr) * 64 + kk * 32 + lk * 8];
#pragma unroll
      for (int ci = 0; ci < 4; ++ci)
        b[ci] = *(const bf16x8*)&Bs[(wc * 64 + ci * 16 + lr) * 64 + kk * 32 + lk * 8];
#pragma unroll
      for (int fi = 0; fi < 4; ++fi)
#pragma unroll
        for (int ci = 0; ci < 4; ++ci)
          acc[fi][ci] = __builtin_amdgcn_mfma_f32_16x16x32_bf16(a[fi], b[ci], acc[fi][ci], 0, 0, 0);
    }
    __syncthreads();
  }
#pragma unroll
  for (int ci = 0; ci < 4; ++ci) {
    int col = bn * 128 + wc * 64 + ci * 16 + lr;
    float b = bias[col];
#pragma unroll
    for (int fi = 0; fi < 4; ++fi)
#pragma unroll
      for (int j = 0; j < 4; ++j) {
        int m = bm * 128 + wr * 64 + fi * 16 + lk * 4 + j;
        out[(size_t)m * E_ + col] = acc[fi][ci][j] + b;
      }
  }
}

extern "C" void kernel_launch(void* const* d_in, const int* in_sizes, int n_in,
                              void* d_out, int out_size, void* d_ws, size_t ws_size,
                              hipStream_t stream) {
  const float* qin = (const float*)d_in[0];
  const float* kin = (const float*)d_in[1];
  const float* vin = (const float*)d_in[2];
  const float* wi  = (const float*)d_in[3];
  const float* bi  = (const float*)d_in[4];
  const float* wo  = (const float*)d_in[5];
  const float* bo  = (const float*)d_in[6];
  float* out = (float*)d_out;                       // (L,NB,E) fp32
  float* attnw = out + (size_t)L_ * NB * E_;        // (NB,L,S) fp32

  short* wqkv = (short*)d_ws;                       // 3E*E bf16
  short* wout = wqkv + (size_t)3 * E_ * E_;         // E*E bf16
  short* qh = wout + (size_t)E_ * E_;               // NB*H*L*D bf16
  short* kh = qh + (size_t)NB * L_ * E_;
  short* vt = kh + (size_t)NB * L_ * E_;            // NB*H*(S/32)*D*32 bf16 (blocked V^T)
  float* rl = (float*)(vt + (size_t)NB * L_ * E_);  // NB*H*L fp32
  short* xq = (short*)(rl + (size_t)NB * H_ * L_);  // L*NB*E bf16 activations
  short* xk = xq + (size_t)L_ * NB * E_;
  short* xv = xk + (size_t)L_ * NB * E_;
  short* ctx = xq;  // alias: xq dead after k_qkv, ctx written by k_attn

  k_convert<<<2048, 256, 0, stream>>>(wi, wo, qin, kin, vin, wqkv, wout, xq, xk, xv);
  k_qkv<<<1536, 256, 0, stream>>>(xq, xk, xv, wqkv, bi, qh, kh, vt);
  k_stats<<<1024, 256, 0, stream>>>(qh, kh, rl);
  k_attn<<<256, 1024, 131072, stream>>>(qh, kh, vt, rl, attnw, ctx);
  k_out<<<512, 256, 0, stream>>>(ctx, wout, bo, out);
}